// Round 17
// baseline (150.229 us; speedup 1.0000x reference)
//
#include <hip/hip_runtime.h>

#define BATCH 128
#define H 224
#define W 224
#define PH1 112
#define PH2 56
#define FLAT (PH2*PH2*10)   // 31360
#define KC 64               // fc1 K-chunk

// ---------------- Kernel A: conv1(3x3,3->8,SAME)+bias+relu+maxpool2, planar-LDS ----------------
// v9 = v8 + occupancy forcing. v8 measured 50.6us with VGPR=32: the compiler
// squeezed arch VGPRs to chase 8 blocks/CU and shuttled acc[4][8] through
// AGPRs (v_accvgpr_* VALU traffic, ~2x inst inflation). conv2 (40KB LDS ->
// 4 blocks/CU budget, ~1.2 inst/FMA) shows the fix: pad LDS past 32KB and
// declare launch_bounds(256,4) so 4 blocks/CU is the hard cap and there is
// no occupancy payoff for register squeezing.
#define C1_RLEN 232
#define C1_PLANE (6*C1_RLEN)   // 1392
#define C1_PAD 4096            // dead tail: forces LDS > 32KB -> 4 blocks/CU
__global__ __launch_bounds__(256, 4) void k_conv1(const float* __restrict__ x,
        const float* __restrict__ w, const float* __restrict__ bias,
        float* __restrict__ pool1) {
    __shared__ float slab[3*C1_PLANE + C1_PAD];   // 8272 f = 33.1 KB
    __shared__ float ws[216];
    __shared__ float bs[8];
    int tid = threadIdx.x;
    int rg = blockIdx.x % 56;            // pooled rows 2rg, 2rg+1
    int b  = blockIdx.x / 56;

    if (tid < 216) ws[tid] = w[tid];
    if (tid >= 216 && tid < 224) bs[tid-216] = bias[tid-216];
    // keep the pad tail live so it can't be dropped (blockIdx guard: never true)
    if (b == 0x7fffffff) slab[3*C1_PLANE + (tid & 1023)] = 1.f;
    // zero the two pad cells per (ch,row): idx 3 (col -1) and idx 228 (col 224)
    if (tid < 36) {
        int ch = tid / 12, rem = tid % 12;
        int r = rem >> 1, col = (rem & 1) ? 228 : 3;
        slab[ch*C1_PLANE + r*C1_RLEN + col] = 0.f;
    }
    // stage: 6 rows x 56 segments (4 px each). floats 12s..12s+11 of row iy.
    int row0 = 4*rg - 1;
    const float* xb = x + (size_t)b*H*W*3;
    for (int i = tid; i < 336; i += 256) {
        int r = i / 56, s = i % 56;
        int iy = row0 + r;
        float4 g0 = make_float4(0,0,0,0), g1 = g0, g2 = g0;
        if (iy >= 0 && iy < H) {
            const float4* src = (const float4*)(xb + (size_t)iy*672 + 12*s);
            g0 = src[0]; g1 = src[1]; g2 = src[2];
        }
        float* dst = &slab[r*C1_RLEN + 4 + 4*s];
        *(float4*)(dst + 0*C1_PLANE) = make_float4(g0.x, g0.w, g1.z, g2.y);  // ch0
        *(float4*)(dst + 1*C1_PLANE) = make_float4(g0.y, g1.x, g1.w, g2.z);  // ch1
        *(float4*)(dst + 2*C1_PLANE) = make_float4(g0.z, g1.y, g2.x, g2.w);  // ch2
    }
    __syncthreads();

    if (tid >= 224) return;
    int dpr = tid / 112, pc = tid % 112;

    float acc[4][8];
    #pragma unroll
    for (int p = 0; p < 4; ++p)
        #pragma unroll
        for (int co = 0; co < 8; ++co) acc[p][co] = bs[co];

    #pragma unroll
    for (int ci = 0; ci < 3; ++ci) {
        // window cols = slab idx 3+2pc .. 6+2pc; read even-aligned idx 2+2pc..7+2pc
        float v[4][4];
        #pragma unroll
        for (int rr = 0; rr < 4; ++rr) {
            const float2* lp = (const float2*)&slab[ci*C1_PLANE + (2*dpr+rr)*C1_RLEN + 2 + 2*pc];
            float2 a = lp[0], m = lp[1], c = lp[2];
            v[rr][0] = a.y; v[rr][1] = m.x; v[rr][2] = m.y; v[rr][3] = c.x;
        }
        #pragma unroll
        for (int ky = 0; ky < 3; ++ky)
        #pragma unroll
        for (int kx = 0; kx < 3; ++kx) {
            const float* wp = &ws[((ky*3+kx)*3+ci)*8];
            float wv[8];
            #pragma unroll
            for (int co = 0; co < 8; ++co) wv[co] = wp[co];
            #pragma unroll
            for (int cy = 0; cy < 2; ++cy)
            #pragma unroll
            for (int cx = 0; cx < 2; ++cx) {
                float vin = v[cy+ky][cx+kx];
                #pragma unroll
                for (int co = 0; co < 8; ++co)
                    acc[cy*2+cx][co] = fmaf(vin, wv[co], acc[cy*2+cx][co]);
            }
        }
    }

    float pooled[8];
    #pragma unroll
    for (int co = 0; co < 8; ++co)
        pooled[co] = fmaxf(fmaxf(fmaxf(fmaxf(0.f, acc[0][co]), acc[1][co]), acc[2][co]), acc[3][co]);
    int pr = 2*rg + dpr;
    float4* o4 = (float4*)(pool1 + ((size_t)((b*PH1 + pr)*PH1 + pc))*8);
    o4[0] = make_float4(pooled[0], pooled[1], pooled[2], pooled[3]);
    o4[1] = make_float4(pooled[4], pooled[5], pooled[6], pooled[7]);
}

// ---------------- Kernel B: conv2(3x3,8->10,SAME)+bias+relu+maxpool2, LDS-tiled ----------------
#define C2_ROWS 10
#define C2_COLS 114
#define C2_PLANE (C2_ROWS*C2_COLS)   // 1140
__global__ __launch_bounds__(256) void k_conv2(const float* __restrict__ pool1,
        const float* __restrict__ w, const float* __restrict__ bias,
        float* __restrict__ pool2) {
    __shared__ float lds[8*C2_PLANE];   // 9120 f = 36.5 KB
    __shared__ float ws[720];
    __shared__ float bs[10];
    int tid = threadIdx.x;
    int rg = blockIdx.x % 14;           // row group: pooled rows 4*rg .. 4*rg+3
    int b  = blockIdx.x / 14;

    for (int i = tid; i < 720; i += 256) ws[i] = w[i];
    if (tid < 10) bs[tid] = bias[tid];
    if (tid < 160) {
        int ci = tid / 20, rem = tid % 20;
        int r = rem >> 1, col = (rem & 1) ? (C2_COLS-1) : 0;
        lds[ci*C2_PLANE + r*C2_COLS + col] = 0.f;
    }
    int row0 = 8*rg - 1;
    for (int i = tid; i < 2240; i += 256) {
        int r = i / 224, rem = i % 224;
        int pix = rem >> 1, half = rem & 1;
        int iy = row0 + r;
        float4 v = make_float4(0.f,0.f,0.f,0.f);
        if (iy >= 0 && iy < PH1)
            v = *(const float4*)(pool1 + ((size_t)((b*PH1 + iy)*PH1 + pix))*8 + half*4);
        float* dst = lds + (half*4)*C2_PLANE + r*C2_COLS + (pix+1);
        dst[0*C2_PLANE] = v.x;
        dst[1*C2_PLANE] = v.y;
        dst[2*C2_PLANE] = v.z;
        dst[3*C2_PLANE] = v.w;
    }
    __syncthreads();

    if (tid >= 224) return;
    int dpr = tid / 56, pc = tid % 56;
    int rbase = 2*dpr;
    int cbase = 2*pc;

    float acc[4][10];
    #pragma unroll
    for (int p = 0; p < 4; ++p)
        #pragma unroll
        for (int co = 0; co < 10; ++co) acc[p][co] = bs[co];

    #pragma unroll
    for (int ci = 0; ci < 8; ++ci) {
        float v[4][4];
        #pragma unroll
        for (int r = 0; r < 4; ++r) {
            const float2* lp2 = (const float2*)(lds + ci*C2_PLANE + (rbase+r)*C2_COLS + cbase);
            float2 a = lp2[0], c = lp2[1];
            v[r][0] = a.x; v[r][1] = a.y; v[r][2] = c.x; v[r][3] = c.y;
        }
        #pragma unroll
        for (int ky = 0; ky < 3; ++ky)
        #pragma unroll
        for (int kx = 0; kx < 3; ++kx) {
            const float* wp = &ws[((ky*3+kx)*8+ci)*10];
            float wv[10];
            #pragma unroll
            for (int co = 0; co < 10; ++co) wv[co] = wp[co];
            #pragma unroll
            for (int cy = 0; cy < 2; ++cy)
            #pragma unroll
            for (int cx = 0; cx < 2; ++cx) {
                float vv = v[cy+ky][cx+kx];
                #pragma unroll
                for (int co = 0; co < 10; ++co)
                    acc[cy*2+cx][co] = fmaf(vv, wv[co], acc[cy*2+cx][co]);
            }
        }
    }

    float pooled[10];
    #pragma unroll
    for (int co = 0; co < 10; ++co)
        pooled[co] = fmaxf(fmaxf(fmaxf(fmaxf(0.f, acc[0][co]), acc[1][co]), acc[2][co]), acc[3][co]);
    int pr = 4*rg + dpr;
    float2* o2 = (float2*)(pool2 + ((size_t)(b*PH2 + pr)*PH2 + pc)*10);
    #pragma unroll
    for (int i = 0; i < 5; ++i) o2[i] = make_float2(pooled[2*i], pooled[2*i+1]);
}

// ---------------- Kernel C: fc1 split-K partial GEMM (atomics into t_raw) ----------------
__global__ __launch_bounds__(256) void k_fc1(const float* __restrict__ pool2,
        const float* __restrict__ w, float* __restrict__ t_raw) {
    __shared__ float Ash[BATCH][KC];   // 32 KB
    __shared__ float Wsh[KC][32];      // 8 KB
    int tid = threadIdx.x;
    int k0 = blockIdx.x * KC;          // 490 blocks, 490*64 = 31360
    for (int i = tid; i < KC*32; i += 256) {
        int k = i >> 5, n = i & 31;
        Wsh[k][n] = w[(size_t)(k0 + k)*32 + n];
    }
    {
        int k = tid & 63, br = tid >> 6;
        for (int p = 0; p < 32; ++p) {
            int b = p*4 + br;
            Ash[b][k] = pool2[(size_t)b*FLAT + k0 + k];
        }
    }
    __syncthreads();
    int n = tid & 31, bg = tid >> 5;
    for (int bo = 0; bo < 16; ++bo) {
        int b = bo*8 + bg;
        float acc = 0.f;
        #pragma unroll
        for (int k = 0; k < KC; ++k) acc = fmaf(Ash[b][k], Wsh[k][n], acc);
        atomicAdd(&t_raw[b*32 + n], acc);
    }
}

// ---------------- Kernel D: relu(t+fc1_b) @ fc2_w + fc2_b -> theta [128,6] ----------------
__global__ __launch_bounds__(128) void k_fc2(const float* __restrict__ t_raw,
        const float* __restrict__ fc1_b,
        const float* __restrict__ w, const float* __restrict__ bias,
        float* __restrict__ theta) {
    int b = threadIdx.x;  // 128 threads, 1 block
    float acc[6];
    #pragma unroll
    for (int j = 0; j < 6; ++j) acc[j] = bias[j];
    for (int i = 0; i < 32; ++i) {
        float t = fmaxf(t_raw[b*32 + i] + fc1_b[i], 0.f);
        #pragma unroll
        for (int j = 0; j < 6; ++j) acc[j] = fmaf(t, w[i*6 + j], acc[j]);
    }
    #pragma unroll
    for (int j = 0; j < 6; ++j) theta[b*6 + j] = acc[j];
}

// ---------------- Kernel E: affine grid + bilinear sample (v1, measured best) ----------------
__global__ __launch_bounds__(256) void k_sample(const float* __restrict__ x,
        const float* __restrict__ theta, float* __restrict__ out) {
    int gid = blockIdx.x * 256 + threadIdx.x;   // 128*224*224 = 6,422,528
    int wi = gid % W;
    int t2 = gid / W;
    int hi = t2 % H;
    int b  = t2 / H;
    const float* th = theta + b*6;
    float xt = -1.0f + wi * (2.0f/223.0f);
    float yt = -1.0f + hi * (2.0f/223.0f);
    float gx = th[0]*xt + th[1]*yt + th[2];
    float gy = th[3]*xt + th[4]*yt + th[5];
    float x_s = (gx + 1.0f) * 0.5f * 223.0f;
    float y_s = (gy + 1.0f) * 0.5f * 223.0f;
    int x0 = min(max((int)floorf(x_s), 0), W-1);
    int x1 = min(x0 + 1, W-1);
    int y0 = min(max((int)floorf(y_s), 0), H-1);
    int y1 = min(y0 + 1, H-1);
    float x0f = (float)x0, x1f = (float)x1, y0f = (float)y0, y1f = (float)y1;
    float wa = (x1f - x_s) * (y1f - y_s);
    float wb = (x1f - x_s) * (y_s - y0f);
    float wc = (x_s - x0f) * (y1f - y_s);
    float wd = (x_s - x0f) * (y_s - y0f);
    const float* base = x + (size_t)b*H*W*3;
    const float* p00 = base + (size_t)(y0*W + x0)*3;
    const float* p01 = base + (size_t)(y1*W + x0)*3;
    const float* p10 = base + (size_t)(y0*W + x1)*3;
    const float* p11 = base + (size_t)(y1*W + x1)*3;
    float* o = out + (size_t)gid*3;
    #pragma unroll
    for (int c = 0; c < 3; ++c)
        o[c] = wa*p00[c] + wb*p01[c] + wc*p10[c] + wd*p11[c];
}

extern "C" void kernel_launch(void* const* d_in, const int* in_sizes, int n_in,
                              void* d_out, int out_size, void* d_ws, size_t ws_size,
                              hipStream_t stream) {
    const float* x       = (const float*)d_in[0];
    const float* conv1_w = (const float*)d_in[1];
    const float* conv1_b = (const float*)d_in[2];
    const float* conv2_w = (const float*)d_in[3];
    const float* conv2_b = (const float*)d_in[4];
    const float* fc1_w   = (const float*)d_in[5];
    const float* fc1_b   = (const float*)d_in[6];
    const float* fc2_w   = (const float*)d_in[7];
    const float* fc2_b   = (const float*)d_in[8];
    float* out = (float*)d_out;

    // Scratch layout: pool1 + pool2 live INSIDE d_out (fully consumed before the
    // sampler overwrites d_out). d_ws holds only fc activations (~20 KB).
    float* pool1 = out;
    float* pool2 = out + 12845056;
    float* t_raw = (float*)d_ws;            // 128*32 f32
    float* theta = t_raw + BATCH*32;        // 128*6  f32

    hipMemsetAsync(t_raw, 0, BATCH*32*sizeof(float), stream);
    k_conv1<<<7168, 256, 0, stream>>>(x, conv1_w, conv1_b, pool1);
    k_conv2<<<1792, 256, 0, stream>>>(pool1, conv2_w, conv2_b, pool2);
    k_fc1<<<490, 256, 0, stream>>>(pool2, fc1_w, t_raw);
    k_fc2<<<1, 128, 0, stream>>>(t_raw, fc1_b, fc2_w, fc2_b, theta);
    k_sample<<<25088, 256, 0, stream>>>(x, theta, out);
}

// Round 18
// 143.052 us; speedup vs baseline: 1.0502x; 1.0502x over previous
//
#include <hip/hip_runtime.h>

#define BATCH 128
#define H 224
#define W 224
#define PH1 112
#define PH2 56
#define FLAT (PH2*PH2*10)   // 31360
#define KC 64               // fc1 K-chunk

// ---------------- Kernel A: conv1(3x3,3->8,SAME)+bias+relu+maxpool2, planar-LDS ----------------
// v8 (measured best: 50.6us, VALUBusy 93-96%). Block: 2 pooled rows x 112 cols.
// LDS planar slab [3][6][232]; staging = 3 float4 loads -> register transpose ->
// 3 aligned ds_write_b128 (no div/mod scatter). Compute ci-outer, float2 window
// reads, hoisted wv[8]. Known residual: compiler holds arch-VGPR at 32 and
// shuttles acc through AGPRs (~2x inst inflation); v9's occupancy-forcing fix
// traded away too many waves (56.4us) — v8 stands.
#define C1_RLEN 232
#define C1_PLANE (6*C1_RLEN)   // 1392
__global__ __launch_bounds__(256) void k_conv1(const float* __restrict__ x,
        const float* __restrict__ w, const float* __restrict__ bias,
        float* __restrict__ pool1) {
    __shared__ float slab[3*C1_PLANE];   // 4176 f = 16.7 KB
    __shared__ float ws[216];
    __shared__ float bs[8];
    int tid = threadIdx.x;
    int rg = blockIdx.x % 56;            // pooled rows 2rg, 2rg+1
    int b  = blockIdx.x / 56;

    if (tid < 216) ws[tid] = w[tid];
    if (tid >= 216 && tid < 224) bs[tid-216] = bias[tid-216];
    // zero the two pad cells per (ch,row): idx 3 (col -1) and idx 228 (col 224)
    if (tid < 36) {
        int ch = tid / 12, rem = tid % 12;
        int r = rem >> 1, col = (rem & 1) ? 228 : 3;
        slab[ch*C1_PLANE + r*C1_RLEN + col] = 0.f;
    }
    // stage: 6 rows x 56 segments (4 px each). floats 12s..12s+11 of row iy.
    int row0 = 4*rg - 1;
    const float* xb = x + (size_t)b*H*W*3;
    for (int i = tid; i < 336; i += 256) {
        int r = i / 56, s = i % 56;
        int iy = row0 + r;
        float4 g0 = make_float4(0,0,0,0), g1 = g0, g2 = g0;
        if (iy >= 0 && iy < H) {
            const float4* src = (const float4*)(xb + (size_t)iy*672 + 12*s);
            g0 = src[0]; g1 = src[1]; g2 = src[2];
        }
        float* dst = &slab[r*C1_RLEN + 4 + 4*s];
        *(float4*)(dst + 0*C1_PLANE) = make_float4(g0.x, g0.w, g1.z, g2.y);  // ch0
        *(float4*)(dst + 1*C1_PLANE) = make_float4(g0.y, g1.x, g1.w, g2.z);  // ch1
        *(float4*)(dst + 2*C1_PLANE) = make_float4(g0.z, g1.y, g2.x, g2.w);  // ch2
    }
    __syncthreads();

    if (tid >= 224) return;
    int dpr = tid / 112, pc = tid % 112;

    float acc[4][8];
    #pragma unroll
    for (int p = 0; p < 4; ++p)
        #pragma unroll
        for (int co = 0; co < 8; ++co) acc[p][co] = bs[co];

    #pragma unroll
    for (int ci = 0; ci < 3; ++ci) {
        // window cols = slab idx 3+2pc .. 6+2pc; read even-aligned idx 2+2pc..7+2pc
        float v[4][4];
        #pragma unroll
        for (int rr = 0; rr < 4; ++rr) {
            const float2* lp = (const float2*)&slab[ci*C1_PLANE + (2*dpr+rr)*C1_RLEN + 2 + 2*pc];
            float2 a = lp[0], m = lp[1], c = lp[2];
            v[rr][0] = a.y; v[rr][1] = m.x; v[rr][2] = m.y; v[rr][3] = c.x;
        }
        #pragma unroll
        for (int ky = 0; ky < 3; ++ky)
        #pragma unroll
        for (int kx = 0; kx < 3; ++kx) {
            const float* wp = &ws[((ky*3+kx)*3+ci)*8];
            float wv[8];
            #pragma unroll
            for (int co = 0; co < 8; ++co) wv[co] = wp[co];
            #pragma unroll
            for (int cy = 0; cy < 2; ++cy)
            #pragma unroll
            for (int cx = 0; cx < 2; ++cx) {
                float vin = v[cy+ky][cx+kx];
                #pragma unroll
                for (int co = 0; co < 8; ++co)
                    acc[cy*2+cx][co] = fmaf(vin, wv[co], acc[cy*2+cx][co]);
            }
        }
    }

    float pooled[8];
    #pragma unroll
    for (int co = 0; co < 8; ++co)
        pooled[co] = fmaxf(fmaxf(fmaxf(fmaxf(0.f, acc[0][co]), acc[1][co]), acc[2][co]), acc[3][co]);
    int pr = 2*rg + dpr;
    float4* o4 = (float4*)(pool1 + ((size_t)((b*PH1 + pr)*PH1 + pc))*8);
    o4[0] = make_float4(pooled[0], pooled[1], pooled[2], pooled[3]);
    o4[1] = make_float4(pooled[4], pooled[5], pooled[6], pooled[7]);
}

// ---------------- Kernel B: conv2(3x3,8->10,SAME)+bias+relu+maxpool2, LDS-tiled ----------------
// + __launch_bounds__(256,4): 36.5KB LDS already caps us at 4 blocks/CU, so a
// 128-VGPR budget costs nothing — removes the allocator's incentive to squeeze
// arch-VGPRs and shuttle acc[4][10] through AGPRs (conv1-v8's diagnosed 2x
// inst inflation; here the occupancy tradeoff that sank conv1-v9 doesn't exist).
#define C2_ROWS 10
#define C2_COLS 114
#define C2_PLANE (C2_ROWS*C2_COLS)   // 1140
__global__ __launch_bounds__(256, 4) void k_conv2(const float* __restrict__ pool1,
        const float* __restrict__ w, const float* __restrict__ bias,
        float* __restrict__ pool2) {
    __shared__ float lds[8*C2_PLANE];   // 9120 f = 36.5 KB
    __shared__ float ws[720];
    __shared__ float bs[10];
    int tid = threadIdx.x;
    int rg = blockIdx.x % 14;           // row group: pooled rows 4*rg .. 4*rg+3
    int b  = blockIdx.x / 14;

    for (int i = tid; i < 720; i += 256) ws[i] = w[i];
    if (tid < 10) bs[tid] = bias[tid];
    if (tid < 160) {
        int ci = tid / 20, rem = tid % 20;
        int r = rem >> 1, col = (rem & 1) ? (C2_COLS-1) : 0;
        lds[ci*C2_PLANE + r*C2_COLS + col] = 0.f;
    }
    int row0 = 8*rg - 1;
    for (int i = tid; i < 2240; i += 256) {
        int r = i / 224, rem = i % 224;
        int pix = rem >> 1, half = rem & 1;
        int iy = row0 + r;
        float4 v = make_float4(0.f,0.f,0.f,0.f);
        if (iy >= 0 && iy < PH1)
            v = *(const float4*)(pool1 + ((size_t)((b*PH1 + iy)*PH1 + pix))*8 + half*4);
        float* dst = lds + (half*4)*C2_PLANE + r*C2_COLS + (pix+1);
        dst[0*C2_PLANE] = v.x;
        dst[1*C2_PLANE] = v.y;
        dst[2*C2_PLANE] = v.z;
        dst[3*C2_PLANE] = v.w;
    }
    __syncthreads();

    if (tid >= 224) return;
    int dpr = tid / 56, pc = tid % 56;
    int rbase = 2*dpr;
    int cbase = 2*pc;

    float acc[4][10];
    #pragma unroll
    for (int p = 0; p < 4; ++p)
        #pragma unroll
        for (int co = 0; co < 10; ++co) acc[p][co] = bs[co];

    #pragma unroll
    for (int ci = 0; ci < 8; ++ci) {
        float v[4][4];
        #pragma unroll
        for (int r = 0; r < 4; ++r) {
            const float2* lp2 = (const float2*)(lds + ci*C2_PLANE + (rbase+r)*C2_COLS + cbase);
            float2 a = lp2[0], c = lp2[1];
            v[r][0] = a.x; v[r][1] = a.y; v[r][2] = c.x; v[r][3] = c.y;
        }
        #pragma unroll
        for (int ky = 0; ky < 3; ++ky)
        #pragma unroll
        for (int kx = 0; kx < 3; ++kx) {
            const float* wp = &ws[((ky*3+kx)*8+ci)*10];
            float wv[10];
            #pragma unroll
            for (int co = 0; co < 10; ++co) wv[co] = wp[co];
            #pragma unroll
            for (int cy = 0; cy < 2; ++cy)
            #pragma unroll
            for (int cx = 0; cx < 2; ++cx) {
                float vv = v[cy+ky][cx+kx];
                #pragma unroll
                for (int co = 0; co < 10; ++co)
                    acc[cy*2+cx][co] = fmaf(vv, wv[co], acc[cy*2+cx][co]);
            }
        }
    }

    float pooled[10];
    #pragma unroll
    for (int co = 0; co < 10; ++co)
        pooled[co] = fmaxf(fmaxf(fmaxf(fmaxf(0.f, acc[0][co]), acc[1][co]), acc[2][co]), acc[3][co]);
    int pr = 4*rg + dpr;
    float2* o2 = (float2*)(pool2 + ((size_t)(b*PH2 + pr)*PH2 + pc)*10);
    #pragma unroll
    for (int i = 0; i < 5; ++i) o2[i] = make_float2(pooled[2*i], pooled[2*i+1]);
}

// ---------------- Kernel C: fc1 split-K partial GEMM (atomics into t_raw) ----------------
// + __launch_bounds__(256,4): 40KB LDS caps at 4 blocks/CU anyway.
__global__ __launch_bounds__(256, 4) void k_fc1(const float* __restrict__ pool2,
        const float* __restrict__ w, float* __restrict__ t_raw) {
    __shared__ float Ash[BATCH][KC];   // 32 KB
    __shared__ float Wsh[KC][32];      // 8 KB
    int tid = threadIdx.x;
    int k0 = blockIdx.x * KC;          // 490 blocks, 490*64 = 31360
    for (int i = tid; i < KC*32; i += 256) {
        int k = i >> 5, n = i & 31;
        Wsh[k][n] = w[(size_t)(k0 + k)*32 + n];
    }
    {
        int k = tid & 63, br = tid >> 6;
        for (int p = 0; p < 32; ++p) {
            int b = p*4 + br;
            Ash[b][k] = pool2[(size_t)b*FLAT + k0 + k];
        }
    }
    __syncthreads();
    int n = tid & 31, bg = tid >> 5;
    for (int bo = 0; bo < 16; ++bo) {
        int b = bo*8 + bg;
        float acc = 0.f;
        #pragma unroll
        for (int k = 0; k < KC; ++k) acc = fmaf(Ash[b][k], Wsh[k][n], acc);
        atomicAdd(&t_raw[b*32 + n], acc);
    }
}

// ---------------- Kernel D: relu(t+fc1_b) @ fc2_w + fc2_b -> theta [128,6] ----------------
__global__ __launch_bounds__(128) void k_fc2(const float* __restrict__ t_raw,
        const float* __restrict__ fc1_b,
        const float* __restrict__ w, const float* __restrict__ bias,
        float* __restrict__ theta) {
    int b = threadIdx.x;  // 128 threads, 1 block
    float acc[6];
    #pragma unroll
    for (int j = 0; j < 6; ++j) acc[j] = bias[j];
    for (int i = 0; i < 32; ++i) {
        float t = fmaxf(t_raw[b*32 + i] + fc1_b[i], 0.f);
        #pragma unroll
        for (int j = 0; j < 6; ++j) acc[j] = fmaf(t, w[i*6 + j], acc[j]);
    }
    #pragma unroll
    for (int j = 0; j < 6; ++j) theta[b*6 + j] = acc[j];
}

// ---------------- Kernel E: affine grid + bilinear sample (v1, measured best) ----------------
__global__ __launch_bounds__(256) void k_sample(const float* __restrict__ x,
        const float* __restrict__ theta, float* __restrict__ out) {
    int gid = blockIdx.x * 256 + threadIdx.x;   // 128*224*224 = 6,422,528
    int wi = gid % W;
    int t2 = gid / W;
    int hi = t2 % H;
    int b  = t2 / H;
    const float* th = theta + b*6;
    float xt = -1.0f + wi * (2.0f/223.0f);
    float yt = -1.0f + hi * (2.0f/223.0f);
    float gx = th[0]*xt + th[1]*yt + th[2];
    float gy = th[3]*xt + th[4]*yt + th[5];
    float x_s = (gx + 1.0f) * 0.5f * 223.0f;
    float y_s = (gy + 1.0f) * 0.5f * 223.0f;
    int x0 = min(max((int)floorf(x_s), 0), W-1);
    int x1 = min(x0 + 1, W-1);
    int y0 = min(max((int)floorf(y_s), 0), H-1);
    int y1 = min(y0 + 1, H-1);
    float x0f = (float)x0, x1f = (float)x1, y0f = (float)y0, y1f = (float)y1;
    float wa = (x1f - x_s) * (y1f - y_s);
    float wb = (x1f - x_s) * (y_s - y0f);
    float wc = (x_s - x0f) * (y1f - y_s);
    float wd = (x_s - x0f) * (y_s - y0f);
    const float* base = x + (size_t)b*H*W*3;
    const float* p00 = base + (size_t)(y0*W + x0)*3;
    const float* p01 = base + (size_t)(y1*W + x0)*3;
    const float* p10 = base + (size_t)(y0*W + x1)*3;
    const float* p11 = base + (size_t)(y1*W + x1)*3;
    float* o = out + (size_t)gid*3;
    #pragma unroll
    for (int c = 0; c < 3; ++c)
        o[c] = wa*p00[c] + wb*p01[c] + wc*p10[c] + wd*p11[c];
}

extern "C" void kernel_launch(void* const* d_in, const int* in_sizes, int n_in,
                              void* d_out, int out_size, void* d_ws, size_t ws_size,
                              hipStream_t stream) {
    const float* x       = (const float*)d_in[0];
    const float* conv1_w = (const float*)d_in[1];
    const float* conv1_b = (const float*)d_in[2];
    const float* conv2_w = (const float*)d_in[3];
    const float* conv2_b = (const float*)d_in[4];
    const float* fc1_w   = (const float*)d_in[5];
    const float* fc1_b   = (const float*)d_in[6];
    const float* fc2_w   = (const float*)d_in[7];
    const float* fc2_b   = (const float*)d_in[8];
    float* out = (float*)d_out;

    // Scratch layout: pool1 + pool2 live INSIDE d_out (fully consumed before the
    // sampler overwrites d_out). d_ws holds only fc activations (~20 KB).
    float* pool1 = out;
    float* pool2 = out + 12845056;
    float* t_raw = (float*)d_ws;            // 128*32 f32
    float* theta = t_raw + BATCH*32;        // 128*6  f32

    hipMemsetAsync(t_raw, 0, BATCH*32*sizeof(float), stream);
    k_conv1<<<7168, 256, 0, stream>>>(x, conv1_w, conv1_b, pool1);
    k_conv2<<<1792, 256, 0, stream>>>(pool1, conv2_w, conv2_b, pool2);
    k_fc1<<<490, 256, 0, stream>>>(pool2, fc1_w, t_raw);
    k_fc2<<<1, 128, 0, stream>>>(t_raw, fc1_b, fc2_w, fc2_b, theta);
    k_sample<<<25088, 256, 0, stream>>>(x, theta, out);
}